// Round 7
// baseline (1176.173 us; speedup 1.0000x reference)
//
#include <hip/hip_runtime.h>

#define B_ 16
#define T_ 128
#define OBS_ 64
#define SLOTS_ 67
#define E_ 32
#define H_ 4
#define HD_ 8
#define FFN_ 64

typedef _Float16 h2 __attribute__((ext_vector_type(2)));
typedef _Float16 h8 __attribute__((ext_vector_type(8)));
union H8 { h8 v; h2 h[4]; };

// fp16 weight block layout (halves): Wq 0 | Wk 1024 | Wv 2048 | Wo 3072 |
// Wg 4096 | Wvl 6144 | Wout 8192  (10240 halves per transformer block)
#define WBLK 10240
#define X_BYTES (B_ * T_ * SLOTS_ * E_ * 4)  // 17,563,648

__device__ __forceinline__ float red32(float v) {
  v += __shfl_xor(v, 16); v += __shfl_xor(v, 8); v += __shfl_xor(v, 4);
  v += __shfl_xor(v, 2);  v += __shfl_xor(v, 1);
  return v;
}
__device__ __forceinline__ float red8(float v) {
  v += __shfl_xor(v, 4); v += __shfl_xor(v, 2); v += __shfl_xor(v, 1);
  return v;
}
__device__ __forceinline__ float fdot2(h2 a, h2 b, float c) {
  return __builtin_amdgcn_fdot2(a, b, c, false);
}
__device__ __forceinline__ h2 pkrtz(float x, float y) {
  return __builtin_bit_cast(h2, __builtin_amdgcn_cvt_pkrtz(x, y));
}

// ---------------- weight pre-conversion to fp16 ----------------
struct WPtrs {
  const float *sWq, *sWk, *sWv, *sWo, *sWg, *sWvl, *sWout;
  const float *tWq, *tWk, *tWv, *tWo, *tWg, *tWvl, *tWout;
};

__global__ __launch_bounds__(256) void cvt_weights_kernel(WPtrs p, _Float16* dst) {
  int i = blockIdx.x * 256 + threadIdx.x;  // pair index
  const int total_pairs = 5 * WBLK / 2;    // 25600
  if (i >= total_pairs) return;
  int blk = i / (WBLK / 2);
  int f = (i % (WBLK / 2)) * 2;  // float offset within block's 10240
  bool sp = blk < 3;
  int bi = sp ? blk : blk - 3;
  const float* src;
  int o;
  if (f < 1024)      { src = (sp ? p.sWq : p.tWq) + bi * 1024;  o = f; }
  else if (f < 2048) { src = (sp ? p.sWk : p.tWk) + bi * 1024;  o = f - 1024; }
  else if (f < 3072) { src = (sp ? p.sWv : p.tWv) + bi * 1024;  o = f - 2048; }
  else if (f < 4096) { src = (sp ? p.sWo : p.tWo) + bi * 1024;  o = f - 3072; }
  else if (f < 6144) { src = (sp ? p.sWg : p.tWg) + bi * 2048;  o = f - 4096; }
  else if (f < 8192) { src = (sp ? p.sWvl : p.tWvl) + bi * 2048; o = f - 6144; }
  else               { src = (sp ? p.sWout : p.tWout) + bi * 2048; o = f - 8192; }
  ((h2*)dst)[i] = pkrtz(src[o], src[o + 1]);
}

// ---------------- embed + input rmsnorm ----------------
__global__ __launch_bounds__(256) void embed_kernel(
    const float* __restrict__ obs, const float* __restrict__ Wval,
    const float* __restrict__ bval, const float* __restrict__ innw,
    const float* __restrict__ dimemb, const float* __restrict__ cls,
    float* __restrict__ X) {
  int tok = blockIdx.x * 8 + (threadIdx.x >> 5);
  int e = threadIdx.x & 31;
  const int total = B_ * T_ * SLOTS_;
  if (tok >= total) return;
  int slot = tok % SLOTS_;
  int bt = tok / SLOTS_;
  float v;
  if (slot < OBS_) {
    float o = obs[bt * OBS_ + slot];
    v = o * Wval[e] + bval[e] + dimemb[slot * E_ + e];
  } else {
    v = cls[(slot - OBS_) * E_ + e];
  }
  float ss = red32(v * v);
  X[tok * E_ + e] = v * rsqrtf(ss * (1.0f / E_) + 1e-6f) * innw[e];
}

// ---------------- one full attention block per workgroup ----------------
// LDS (halves): [hbuf S*32 | qbuf S*32 | kbuf S*32].
// hbuf: h -> o -> h2. qbuf: q -> v. ffn (S*64) overlays qbuf+kbuf.
// Temporal: 24576 B -> 6 blocks/CU (LDS cap, needs 4.19);
// spatial: 12864 B -> needs 8 blocks/CU => VGPR must be <= 64.
template <int S, bool TEMPORAL>
__global__ __launch_bounds__(256, 8) __attribute__((amdgpu_waves_per_eu(8)))
void attn_block_kernel(
    float* __restrict__ X, const _Float16* __restrict__ W16,
    const float* __restrict__ norm4, const float* __restrict__ qkn) {
  constexpr int SREG = (S + 7) / 8;
  __shared__ __align__(16) _Float16 smem[S * 96];
  _Float16* hbuf = smem;            // h -> o -> h2
  _Float16* qh = smem + S * 32;     // q -> v
  _Float16* kh = smem + S * 64;     // k
  _Float16* ffnb = qh;              // ffn overlay (S*64 halves)

  const int tid = threadIdx.x;
  const int e = tid & 31;
  const int srow = tid >> 5;

  int base, stride;
  if (TEMPORAL) {
    int b = blockIdx.x / SLOTS_;
    int slot = blockIdx.x % SLOTS_;
    base = (b * T_ * SLOTS_ + slot) * E_;
    stride = SLOTS_ * E_;
  } else {
    base = blockIdx.x * S * E_;
    stride = E_;
  }

  const float nw0 = norm4[e], nw1 = norm4[E_ + e], nw2 = norm4[2 * E_ + e],
              nw3 = norm4[3 * E_ + e];

  // ---- phase 1: x -> regs; h = rmsnorm(x) -> hbuf (fp16) ----
  float xr[SREG];
#pragma unroll
  for (int k = 0; k < SREG; k++) {
    int s = srow + 8 * k;
    if (S % 8 == 0 || s < S) {
      xr[k] = X[base + s * stride + e];
      float ss = red32(xr[k] * xr[k]);
      hbuf[s * 32 + e] = (_Float16)(xr[k] * rsqrtf(ss * (1.0f / E_) + 1e-6f) * nw0);
    }
  }
  __syncthreads();

  const int hd = e & 7;
  float theta = 0.f;
  if (TEMPORAL) theta = exp2f(-(float)(hd & 3) * 3.3219280948873623f);

  // ---- phase 2a: q = rmsnorm_head(h @ Wq) (+RoPE) -> qh ----
  {
    const float qw = qkn[hd];
    const float qscale = 0.35355339059327373f * 1.4426950408889634f;  // 1/sqrt(8)*log2e
    H8 wq[4];
    {
      const h8* wqp = (const h8*)(W16 + e * 32);
#pragma unroll
      for (int j = 0; j < 4; j++) wq[j].v = wqp[j];
    }
    for (int idx = tid; idx < S * E_; idx += 256) {
      int s = idx >> 5;
      const H8* hrow = (const H8*)(hbuf + s * 32);
      float aq = 0.f;
#pragma unroll
      for (int c = 0; c < 4; c++) {
        H8 hc = hrow[c];
#pragma unroll
        for (int j = 0; j < 4; j++) aq = fdot2(hc.h[j], wq[c].h[j], aq);
      }
      float qss = red8(aq * aq);
      float qv = aq * rsqrtf(qss * (1.0f / HD_) + 1e-6f) * qw;
      if (TEMPORAL) {
        float ang = (float)s * theta;
        float c, sn;
        __sincosf(ang, &sn, &c);
        float qp2 = __shfl_xor(qv, 4);
        qv = (hd < 4) ? (qv * c - qp2 * sn) : (qv * c + qp2 * sn);
      }
      qh[s * 32 + e] = (_Float16)(qv * qscale);  // exp2-ready
    }
  }

  // ---- phase 2b: k = rmsnorm_head(h @ Wk) (+RoPE) -> kh ----
  {
    const float kw = qkn[8 + hd];
    H8 wk[4];
    {
      const h8* wkp = (const h8*)(W16 + 1024 + e * 32);
#pragma unroll
      for (int j = 0; j < 4; j++) wk[j].v = wkp[j];
    }
    for (int idx = tid; idx < S * E_; idx += 256) {
      int s = idx >> 5;
      const H8* hrow = (const H8*)(hbuf + s * 32);
      float ak = 0.f;
#pragma unroll
      for (int c = 0; c < 4; c++) {
        H8 hc = hrow[c];
#pragma unroll
        for (int j = 0; j < 4; j++) ak = fdot2(hc.h[j], wk[c].h[j], ak);
      }
      float kss = red8(ak * ak);
      float kv = ak * rsqrtf(kss * (1.0f / HD_) + 1e-6f) * kw;
      if (TEMPORAL) {
        float ang = (float)s * theta;
        float c, sn;
        __sincosf(ang, &sn, &c);
        float kp2 = __shfl_xor(kv, 4);
        kv = (hd < 4) ? (kv * c - kp2 * sn) : (kv * c + kp2 * sn);
      }
      kh[s * 32 + e] = (_Float16)kv;
    }
  }
  __syncthreads();

  // ---- phase 3a: stash this thread's q rows in regs ----
  const int g = tid;
  const bool act3 = (2 * g < 4 * S);
  const int qi = g >> 1;
  const int hp = g & 1;  // head pair
  H8 qa, qb;
  if (act3) {
    const _Float16* qp = qh + qi * 32 + hp * 16;
    qa.v = *(const h8*)qp;
    qb.v = *(const h8*)(qp + 8);
  }
  __syncthreads();

  // ---- phase 3b: v = h @ Wv -> qh (overwrites q; q is in regs now) ----
  {
    H8 wv[4];
    {
      const h8* wvp = (const h8*)(W16 + 2048 + e * 32);
#pragma unroll
      for (int j = 0; j < 4; j++) wv[j].v = wvp[j];
    }
    for (int idx = tid; idx < S * E_; idx += 256) {
      int s = idx >> 5;
      const H8* hrow = (const H8*)(hbuf + s * 32);
      float av = 0.f;
#pragma unroll
      for (int c = 0; c < 4; c++) {
        H8 hc = hrow[c];
#pragma unroll
        for (int j = 0; j < 4; j++) av = fdot2(hc.h[j], wv[c].h[j], av);
      }
      qh[s * 32 + e] = (_Float16)av;
    }
  }
  __syncthreads();

  // ---- phase 3c: attention, single-pass softmax (scores bounded) ----
  if (act3) {
    float l0 = 0.f, l1 = 0.f;
    h2 acc[8] = {};
    const _Float16* kp = kh + hp * 16;
    const _Float16* vp = qh + hp * 16;
#pragma unroll 4
    for (int k = 0; k < S; k++) {
      H8 ka, kb, va, vb;
      ka.v = *(const h8*)kp;
      kb.v = *(const h8*)(kp + 8);
      va.v = *(const h8*)vp;
      vb.v = *(const h8*)(vp + 8);
      kp += 32; vp += 32;
      float s0 = fdot2(qa.h[0], ka.h[0], fdot2(qa.h[1], ka.h[1],
                 fdot2(qa.h[2], ka.h[2], fdot2(qa.h[3], ka.h[3], 0.f))));
      float s1 = fdot2(qb.h[0], kb.h[0], fdot2(qb.h[1], kb.h[1],
                 fdot2(qb.h[2], kb.h[2], fdot2(qb.h[3], kb.h[3], 0.f))));
      float e0 = __builtin_amdgcn_exp2f(s0);
      float e1 = __builtin_amdgcn_exp2f(s1);
      l0 += e0; l1 += e1;
      h2 p0 = pkrtz(e0, e0);
      h2 p1 = pkrtz(e1, e1);
      acc[0] += p0 * va.h[0]; acc[1] += p0 * va.h[1];
      acc[2] += p0 * va.h[2]; acc[3] += p0 * va.h[3];
      acc[4] += p1 * vb.h[0]; acc[5] += p1 * vb.h[1];
      acc[6] += p1 * vb.h[2]; acc[7] += p1 * vb.h[3];
    }
    float iv0 = 1.0f / l0, iv1 = 1.0f / l1;
    h2 il0 = pkrtz(iv0, iv0), il1 = pkrtz(iv1, iv1);
    H8 o0, o1;
#pragma unroll
    for (int j = 0; j < 4; j++) {
      o0.h[j] = acc[j] * il0;
      o1.h[j] = acc[4 + j] * il1;
    }
    _Float16* op = hbuf + qi * 32 + hp * 16;  // h is dead; o overwrites
    *(h8*)op = o0.v;
    *(h8*)(op + 8) = o1.v;
  }
  __syncthreads();

  // ---- phase 4: ao = o@Wo (chunk-outer), x += rms(ao); h2 = rms(x) -> hbuf ----
  {
    float p[SREG];
#pragma unroll
    for (int k = 0; k < SREG; k++) p[k] = 0.f;
#pragma unroll
    for (int c = 0; c < 4; c++) {
      H8 wo_c;
      wo_c.v = *(const h8*)(W16 + 3072 + e * 32 + c * 8);
#pragma unroll
      for (int k = 0; k < SREG; k++) {
        int s = srow + 8 * k;
        if (S % 8 == 0 || s < S) {
          H8 oc;
          oc.v = *(const h8*)(hbuf + s * 32 + c * 8);
#pragma unroll
          for (int j = 0; j < 4; j++) p[k] = fdot2(oc.h[j], wo_c.h[j], p[k]);
        }
      }
    }
    // row s is read only by its own half-wave; lockstep => safe to overwrite now
#pragma unroll
    for (int k = 0; k < SREG; k++) {
      int s = srow + 8 * k;
      if (S % 8 == 0 || s < S) {
        float a = p[k];
        float ss = red32(a * a);
        xr[k] += a * rsqrtf(ss * (1.0f / E_) + 1e-6f) * nw1;
        float hx = xr[k];
        float s2s = red32(hx * hx);
        hbuf[s * 32 + e] = (_Float16)(hx * rsqrtf(s2s * (1.0f / E_) + 1e-6f) * nw2);
      }
    }
  }
  __syncthreads();

  // ---- phase 5a: g = silu(h2@Wg) -> ffnb (fp16) ----
  {
    const int f = tid & 63;
    H8 wg[4];
    {
      const h8* a8 = (const h8*)(W16 + 4096 + f * 32);
#pragma unroll
      for (int j = 0; j < 4; j++) wg[j].v = a8[j];
    }
    for (int idx = tid; idx < S * FFN_; idx += 256) {
      int s = idx >> 6;
      const H8* hrow = (const H8*)(hbuf + s * 32);
      float gq = 0.f;
#pragma unroll
      for (int c = 0; c < 4; c++) {
        H8 hc = hrow[c];
#pragma unroll
        for (int j = 0; j < 4; j++) gq = fdot2(hc.h[j], wg[c].h[j], gq);
      }
      float sg = gq / (1.0f + __expf(-gq));
      ffnb[s * FFN_ + f] = (_Float16)sg;
    }
  }
  // same thread owns the same ffnb slots in 5b: no barrier needed

  // ---- phase 5b: ffn = g * (h2@Wvl) -> ffnb (in-place RMW) ----
  {
    const int f = tid & 63;
    H8 wl[4];
    {
      const h8* b8 = (const h8*)(W16 + 6144 + f * 32);
#pragma unroll
      for (int j = 0; j < 4; j++) wl[j].v = b8[j];
    }
    for (int idx = tid; idx < S * FFN_; idx += 256) {
      int s = idx >> 6;
      const H8* hrow = (const H8*)(hbuf + s * 32);
      float vv = 0.f;
#pragma unroll
      for (int c = 0; c < 4; c++) {
        H8 hc = hrow[c];
#pragma unroll
        for (int j = 0; j < 4; j++) vv = fdot2(hc.h[j], wl[c].h[j], vv);
      }
      float sg = (float)ffnb[s * FFN_ + f];
      ffnb[s * FFN_ + f] = (_Float16)(sg * vv);
    }
  }
  __syncthreads();

  // ---- phase 6: out = ffn@Wout^T (chunk-outer), x += rms(out), store ----
  {
    float p[SREG];
#pragma unroll
    for (int k = 0; k < SREG; k++) p[k] = 0.f;
#pragma unroll
    for (int c = 0; c < 8; c++) {
      H8 wh_c;
      wh_c.v = *(const h8*)(W16 + 8192 + e * 64 + c * 8);
#pragma unroll
      for (int k = 0; k < SREG; k++) {
        int s = srow + 8 * k;
        if (S % 8 == 0 || s < S) {
          H8 fc;
          fc.v = *(const h8*)(ffnb + s * FFN_ + c * 8);
#pragma unroll
          for (int j = 0; j < 4; j++) p[k] = fdot2(fc.h[j], wh_c.h[j], p[k]);
        }
      }
    }
#pragma unroll
    for (int k = 0; k < SREG; k++) {
      int s = srow + 8 * k;
      if (S % 8 == 0 || s < S) {
        float a = p[k];
        float ss = red32(a * a);
        xr[k] += a * rsqrtf(ss * (1.0f / E_) + 1e-6f) * nw3;
        X[base + s * stride + e] = xr[k];
      }
    }
  }
}

// ---------------- final norm + output extraction ----------------
__global__ __launch_bounds__(256) void final_kernel(const float* __restrict__ X,
                                                    const float* __restrict__ fnw,
                                                    float* __restrict__ out) {
  int tok = blockIdx.x * 8 + (threadIdx.x >> 5);
  int e = threadIdx.x & 31;
  if (tok >= B_ * 3) return;
  int b = tok / 3, j = tok % 3;
  const float* xp = X + ((size_t)(b * T_ + (T_ - 1)) * SLOTS_ + OBS_ + j) * E_;
  float v = xp[e];
  float ss = red32(v * v);
  out[j * (B_ * E_) + b * E_ + e] = v * rsqrtf(ss * (1.0f / E_) + 1e-6f) * fnw[e];
}

extern "C" void kernel_launch(void* const* d_in, const int* in_sizes, int n_in,
                              void* d_out, int out_size, void* d_ws, size_t ws_size,
                              hipStream_t stream) {
  (void)in_sizes; (void)n_in; (void)out_size; (void)ws_size;
  const float* obs          = (const float*)d_in[0];
  const float* W_val        = (const float*)d_in[1];
  const float* b_val        = (const float*)d_in[2];
  const float* input_norm_w = (const float*)d_in[3];
  const float* dim_embed    = (const float*)d_in[4];
  const float* cls_tokens   = (const float*)d_in[5];
  const float* final_norm_w = (const float*)d_in[6];
  const float* s_n4   = (const float*)d_in[14];
  const float* s_qkn  = (const float*)d_in[15];
  const float* t_n4   = (const float*)d_in[23];
  const float* t_qkn  = (const float*)d_in[24];

  float* X = (float*)d_ws;  // B*T*SLOTS*E floats = 17.56 MB
  _Float16* W16 = (_Float16*)((char*)d_ws + X_BYTES);  // 5*10240 halves
  float* out = (float*)d_out;

  WPtrs wp;
  wp.sWq   = (const float*)d_in[7];
  wp.sWk   = (const float*)d_in[8];
  wp.sWv   = (const float*)d_in[9];
  wp.sWo   = (const float*)d_in[10];
  wp.sWg   = (const float*)d_in[11];
  wp.sWvl  = (const float*)d_in[12];
  wp.sWout = (const float*)d_in[13];
  wp.tWq   = (const float*)d_in[16];
  wp.tWk   = (const float*)d_in[17];
  wp.tWv   = (const float*)d_in[18];
  wp.tWo   = (const float*)d_in[19];
  wp.tWg   = (const float*)d_in[20];
  wp.tWvl  = (const float*)d_in[21];
  wp.tWout = (const float*)d_in[22];
  cvt_weights_kernel<<<100, 256, 0, stream>>>(wp, W16);

  const int total_tokens = B_ * T_ * SLOTS_;
  embed_kernel<<<(total_tokens + 7) / 8, 256, 0, stream>>>(
      obs, W_val, b_val, input_norm_w, dim_embed, cls_tokens, X);

  const int N4 = 4 * E_;   // 128
  const int QN = 2 * HD_;  // 16

#define SPATIAL(i)                                                     \
  attn_block_kernel<SLOTS_, false><<<B_ * T_, 256, 0, stream>>>(       \
      X, W16 + (i)*WBLK, s_n4 + (i)*N4, s_qkn + (i)*QN)
#define TEMPORAL(i)                                                    \
  attn_block_kernel<T_, true><<<B_ * SLOTS_, 256, 0, stream>>>(        \
      X, W16 + (3 + (i)) * WBLK, t_n4 + (i)*N4, t_qkn + (i)*QN)

  SPATIAL(0);
  TEMPORAL(0);
  SPATIAL(1);
  TEMPORAL(1);
  SPATIAL(2);

#undef SPATIAL
#undef TEMPORAL

  final_kernel<<<6, 256, 0, stream>>>(X, final_norm_w, out);
}

// Round 8
// 576.485 us; speedup vs baseline: 2.0402x; 2.0402x over previous
//
#include <hip/hip_runtime.h>

#define B_ 16
#define T_ 128
#define OBS_ 64
#define SLOTS_ 67
#define E_ 32
#define H_ 4
#define HD_ 8
#define FFN_ 64

typedef _Float16 h2 __attribute__((ext_vector_type(2)));
typedef _Float16 h8 __attribute__((ext_vector_type(8)));
union H8 { h8 v; h2 h[4]; };

// fp16 weight block layout (halves): Wq 0 | Wk 1024 | Wv 2048 | Wo 3072 |
// Wg 4096 | Wvl 6144 | Wout 8192  (10240 halves per transformer block)
#define WBLK 10240
#define X_BYTES (B_ * T_ * SLOTS_ * E_ * 4)  // 17,563,648

__device__ __forceinline__ float red32(float v) {
  v += __shfl_xor(v, 16); v += __shfl_xor(v, 8); v += __shfl_xor(v, 4);
  v += __shfl_xor(v, 2);  v += __shfl_xor(v, 1);
  return v;
}
__device__ __forceinline__ float red8(float v) {
  v += __shfl_xor(v, 4); v += __shfl_xor(v, 2); v += __shfl_xor(v, 1);
  return v;
}
__device__ __forceinline__ float fdot2(h2 a, h2 b, float c) {
  return __builtin_amdgcn_fdot2(a, b, c, false);
}
__device__ __forceinline__ h2 pkrtz(float x, float y) {
  return __builtin_bit_cast(h2, __builtin_amdgcn_cvt_pkrtz(x, y));
}

// ---------------- weight pre-conversion to fp16 ----------------
struct WPtrs {
  const float *sWq, *sWk, *sWv, *sWo, *sWg, *sWvl, *sWout;
  const float *tWq, *tWk, *tWv, *tWo, *tWg, *tWvl, *tWout;
};

__global__ __launch_bounds__(256) void cvt_weights_kernel(WPtrs p, _Float16* dst) {
  int i = blockIdx.x * 256 + threadIdx.x;  // pair index
  const int total_pairs = 5 * WBLK / 2;    // 25600
  if (i >= total_pairs) return;
  int blk = i / (WBLK / 2);
  int f = (i % (WBLK / 2)) * 2;  // float offset within block's 10240
  bool sp = blk < 3;
  int bi = sp ? blk : blk - 3;
  const float* src;
  int o;
  if (f < 1024)      { src = (sp ? p.sWq : p.tWq) + bi * 1024;  o = f; }
  else if (f < 2048) { src = (sp ? p.sWk : p.tWk) + bi * 1024;  o = f - 1024; }
  else if (f < 3072) { src = (sp ? p.sWv : p.tWv) + bi * 1024;  o = f - 2048; }
  else if (f < 4096) { src = (sp ? p.sWo : p.tWo) + bi * 1024;  o = f - 3072; }
  else if (f < 6144) { src = (sp ? p.sWg : p.tWg) + bi * 2048;  o = f - 4096; }
  else if (f < 8192) { src = (sp ? p.sWvl : p.tWvl) + bi * 2048; o = f - 6144; }
  else               { src = (sp ? p.sWout : p.tWout) + bi * 2048; o = f - 8192; }
  ((h2*)dst)[i] = pkrtz(src[o], src[o + 1]);
}

// ---------------- embed + input rmsnorm ----------------
__global__ __launch_bounds__(256) void embed_kernel(
    const float* __restrict__ obs, const float* __restrict__ Wval,
    const float* __restrict__ bval, const float* __restrict__ innw,
    const float* __restrict__ dimemb, const float* __restrict__ cls,
    float* __restrict__ X) {
  int tok = blockIdx.x * 8 + (threadIdx.x >> 5);
  int e = threadIdx.x & 31;
  const int total = B_ * T_ * SLOTS_;
  if (tok >= total) return;
  int slot = tok % SLOTS_;
  int bt = tok / SLOTS_;
  float v;
  if (slot < OBS_) {
    float o = obs[bt * OBS_ + slot];
    v = o * Wval[e] + bval[e] + dimemb[slot * E_ + e];
  } else {
    v = cls[(slot - OBS_) * E_ + e];
  }
  float ss = red32(v * v);
  X[tok * E_ + e] = v * rsqrtf(ss * (1.0f / E_) + 1e-6f) * innw[e];
}

// ================= SPATIAL: 2 sequences per block =================
// Per-seq LDS (halves): [h S*32 | q S*32 | k S*32 | v S*32] = S*128.
// ffn (S*64 halves) overlays q+k. Total 2*S*256 B = 34304 B -> 4 blocks/CU.
// Grid = 1024 = exactly 4 blocks/CU -> single fully-resident round.
__global__ __launch_bounds__(256, 4) void attn_spatial_kernel(
    float* __restrict__ X, const _Float16* __restrict__ W16,
    const float* __restrict__ norm4, const float* __restrict__ qkn) {
  constexpr int S = SLOTS_;
  constexpr int SREG = 9;
  constexpr int SEQH = S * 128;  // halves per sequence region
  __shared__ __align__(16) _Float16 smem[2 * SEQH];

  const int tid = threadIdx.x;
  const int e = tid & 31;
  const int srow = tid >> 5;
  const int hd = e & 7;

  const float nw0 = norm4[e], nw1 = norm4[E_ + e], nw2 = norm4[2 * E_ + e],
              nw3 = norm4[3 * E_ + e];

  float xr[2][SREG];

  // ---- phase 1: x -> regs; h = rmsnorm(x) -> h ----
#pragma unroll
  for (int seq = 0; seq < 2; seq++) {
    _Float16* hb = smem + seq * SEQH;
    const float* Xb = X + (blockIdx.x * 2 + seq) * S * E_;
#pragma unroll
    for (int k = 0; k < SREG; k++) {
      int s = srow + 8 * k;
      if (s < S) {
        float x = Xb[s * 32 + e];
        xr[seq][k] = x;
        float ss = red32(x * x);
        hb[s * 32 + e] = (_Float16)(x * rsqrtf(ss * (1.0f / E_) + 1e-6f) * nw0);
      }
    }
  }
  __syncthreads();

  // ---- phase 2a: q = rmsnorm_head(h @ Wq) -> qbuf ----
  {
    const float qw = qkn[hd];
    const float qscale = 0.35355339059327373f * 1.4426950408889634f;  // 1/sqrt(8)*log2e
    H8 wq[4];
    {
      const h8* wqp = (const h8*)(W16 + e * 32);
#pragma unroll
      for (int j = 0; j < 4; j++) wq[j].v = wqp[j];
    }
    for (int seq = 0; seq < 2; seq++) {
      const _Float16* hb = smem + seq * SEQH;
      _Float16* qb = smem + seq * SEQH + S * 32;
      for (int idx = tid; idx < S * E_; idx += 256) {
        int s = idx >> 5;
        const H8* hrow = (const H8*)(hb + s * 32);
        float aq = 0.f;
#pragma unroll
        for (int c = 0; c < 4; c++) {
          H8 hc = hrow[c];
#pragma unroll
          for (int j = 0; j < 4; j++) aq = fdot2(hc.h[j], wq[c].h[j], aq);
        }
        float qss = red8(aq * aq);
        float qv = aq * rsqrtf(qss * (1.0f / HD_) + 1e-6f) * qw;
        qb[s * 32 + e] = (_Float16)(qv * qscale);  // exp2-ready
      }
    }
  }

  // ---- phase 2b: k = rmsnorm_head(h @ Wk) -> kbuf ----
  {
    const float kw = qkn[8 + hd];
    H8 wk[4];
    {
      const h8* wkp = (const h8*)(W16 + 1024 + e * 32);
#pragma unroll
      for (int j = 0; j < 4; j++) wk[j].v = wkp[j];
    }
    for (int seq = 0; seq < 2; seq++) {
      const _Float16* hb = smem + seq * SEQH;
      _Float16* kb = smem + seq * SEQH + S * 64;
      for (int idx = tid; idx < S * E_; idx += 256) {
        int s = idx >> 5;
        const H8* hrow = (const H8*)(hb + s * 32);
        float ak = 0.f;
#pragma unroll
        for (int c = 0; c < 4; c++) {
          H8 hc = hrow[c];
#pragma unroll
          for (int j = 0; j < 4; j++) ak = fdot2(hc.h[j], wk[c].h[j], ak);
        }
        float kss = red8(ak * ak);
        kb[s * 32 + e] = (_Float16)(ak * rsqrtf(kss * (1.0f / HD_) + 1e-6f) * kw);
      }
    }
  }

  // ---- phase 2c: v = h @ Wv -> vbuf ----
  {
    H8 wv[4];
    {
      const h8* wvp = (const h8*)(W16 + 2048 + e * 32);
#pragma unroll
      for (int j = 0; j < 4; j++) wv[j].v = wvp[j];
    }
    for (int seq = 0; seq < 2; seq++) {
      const _Float16* hb = smem + seq * SEQH;
      _Float16* vb = smem + seq * SEQH + S * 96;
      for (int idx = tid; idx < S * E_; idx += 256) {
        int s = idx >> 5;
        const H8* hrow = (const H8*)(hb + s * 32);
        float av = 0.f;
#pragma unroll
        for (int c = 0; c < 4; c++) {
          H8 hc = hrow[c];
#pragma unroll
          for (int j = 0; j < 4; j++) av = fdot2(hc.h[j], wv[c].h[j], av);
        }
        vb[s * 32 + e] = (_Float16)av;
      }
    }
  }
  __syncthreads();

  // ---- phase 3: attention. 268 items (2 seqs x 67 q x 2 head-pairs) on
  // 256 threads; item I: seq = I>=134, qi = (I%134)>>1, hp = I&1.
  // o overwrites h (dead). No shuffles, no barriers inside.
#pragma unroll
  for (int pass = 0; pass < 2; pass++) {
    int I = tid + pass * 256;
    if (I < 4 * S) {  // 268
      int seq = (I >= 2 * S) ? 1 : 0;
      int L = I - seq * 2 * S;
      int qi = L >> 1;
      int hp = L & 1;
      _Float16* sb = smem + seq * SEQH;
      const _Float16* qp = sb + S * 32 + qi * 32 + hp * 16;
      H8 qa, qb;
      qa.v = *(const h8*)qp;
      qb.v = *(const h8*)(qp + 8);
      float l0 = 0.f, l1 = 0.f;
      h2 acc[8] = {};
      const _Float16* kp = sb + S * 64 + hp * 16;
      const _Float16* vp = sb + S * 96 + hp * 16;
      for (int k = 0; k < S; k++) {
        H8 ka, kb, va, vb;
        ka.v = *(const h8*)kp;
        kb.v = *(const h8*)(kp + 8);
        va.v = *(const h8*)vp;
        vb.v = *(const h8*)(vp + 8);
        kp += 32; vp += 32;
        float s0 = fdot2(qa.h[0], ka.h[0], fdot2(qa.h[1], ka.h[1],
                   fdot2(qa.h[2], ka.h[2], fdot2(qa.h[3], ka.h[3], 0.f))));
        float s1 = fdot2(qb.h[0], kb.h[0], fdot2(qb.h[1], kb.h[1],
                   fdot2(qb.h[2], kb.h[2], fdot2(qb.h[3], kb.h[3], 0.f))));
        float e0 = __builtin_amdgcn_exp2f(s0);
        float e1 = __builtin_amdgcn_exp2f(s1);
        l0 += e0; l1 += e1;
        h2 p0 = pkrtz(e0, e0);
        h2 p1 = pkrtz(e1, e1);
        acc[0] += p0 * va.h[0]; acc[1] += p0 * va.h[1];
        acc[2] += p0 * va.h[2]; acc[3] += p0 * va.h[3];
        acc[4] += p1 * vb.h[0]; acc[5] += p1 * vb.h[1];
        acc[6] += p1 * vb.h[2]; acc[7] += p1 * vb.h[3];
      }
      float iv0 = 1.0f / l0, iv1 = 1.0f / l1;
      h2 il0 = pkrtz(iv0, iv0), il1 = pkrtz(iv1, iv1);
      H8 o0, o1;
#pragma unroll
      for (int j = 0; j < 4; j++) {
        o0.h[j] = acc[j] * il0;
        o1.h[j] = acc[4 + j] * il1;
      }
      _Float16* op = sb + qi * 32 + hp * 16;  // h dead -> o
      *(h8*)op = o0.v;
      *(h8*)(op + 8) = o1.v;
    }
  }
  __syncthreads();

  // ---- phase 4: ao = o@Wo (chunk-outer), x += rms(ao); h2 = rms(x) -> h ----
  for (int seq = 0; seq < 2; seq++) {
    _Float16* hb = smem + seq * SEQH;
    float p[SREG];
#pragma unroll
    for (int k = 0; k < SREG; k++) p[k] = 0.f;
#pragma unroll
    for (int c = 0; c < 4; c++) {
      H8 wo_c;
      wo_c.v = *(const h8*)(W16 + 3072 + e * 32 + c * 8);
#pragma unroll
      for (int k = 0; k < SREG; k++) {
        int s = srow + 8 * k;
        if (s < S) {
          H8 oc;
          oc.v = *(const h8*)(hb + s * 32 + c * 8);
#pragma unroll
          for (int j = 0; j < 4; j++) p[k] = fdot2(oc.h[j], wo_c.h[j], p[k]);
        }
      }
    }
    // row s read only by its own half-wave (lockstep) => safe to overwrite
#pragma unroll
    for (int k = 0; k < SREG; k++) {
      int s = srow + 8 * k;
      if (s < S) {
        float a = p[k];
        float ss = red32(a * a);
        xr[seq][k] += a * rsqrtf(ss * (1.0f / E_) + 1e-6f) * nw1;
        float hx = xr[seq][k];
        float s2s = red32(hx * hx);
        hb[s * 32 + e] = (_Float16)(hx * rsqrtf(s2s * (1.0f / E_) + 1e-6f) * nw2);
      }
    }
  }
  __syncthreads();

  // ---- phase 5a: g = silu(h2@Wg) -> ffnb ----
  {
    const int f = tid & 63;
    H8 wg[4];
    {
      const h8* a8 = (const h8*)(W16 + 4096 + f * 32);
#pragma unroll
      for (int j = 0; j < 4; j++) wg[j].v = a8[j];
    }
    for (int seq = 0; seq < 2; seq++) {
      const _Float16* hb = smem + seq * SEQH;
      _Float16* fb = smem + seq * SEQH + S * 32;  // overlays q+k
      for (int idx = tid; idx < S * FFN_; idx += 256) {
        int s = idx >> 6;
        const H8* hrow = (const H8*)(hb + s * 32);
        float gq = 0.f;
#pragma unroll
        for (int c = 0; c < 4; c++) {
          H8 hc = hrow[c];
#pragma unroll
          for (int j = 0; j < 4; j++) gq = fdot2(hc.h[j], wg[c].h[j], gq);
        }
        float sg = gq / (1.0f + __expf(-gq));
        fb[s * FFN_ + f] = (_Float16)sg;
      }
    }
  }
  // same thread owns same slots in 5b: no barrier needed

  // ---- phase 5b: ffn = g * (h2@Wvl) in-place ----
  {
    const int f = tid & 63;
    H8 wl[4];
    {
      const h8* b8 = (const h8*)(W16 + 6144 + f * 32);
#pragma unroll
      for (int j = 0; j < 4; j++) wl[j].v = b8[j];
    }
    for (int seq = 0; seq < 2; seq++) {
      const _Float16* hb = smem + seq * SEQH;
      _Float16* fb = smem + seq * SEQH + S * 32;
      for (int idx = tid; idx < S * FFN_; idx += 256) {
        int s = idx >> 6;
        const H8* hrow = (const H8*)(hb + s * 32);
        float vv = 0.f;
#pragma unroll
        for (int c = 0; c < 4; c++) {
          H8 hc = hrow[c];
#pragma unroll
          for (int j = 0; j < 4; j++) vv = fdot2(hc.h[j], wl[c].h[j], vv);
        }
        float sg = (float)fb[s * FFN_ + f];
        fb[s * FFN_ + f] = (_Float16)(sg * vv);
      }
    }
  }
  __syncthreads();

  // ---- phase 6: out = ffn@Wout^T (chunk-outer), x += rms(out), store ----
  for (int seq = 0; seq < 2; seq++) {
    const _Float16* fb = smem + seq * SEQH + S * 32;
    float* Xb = X + (blockIdx.x * 2 + seq) * S * E_;
    float p[SREG];
#pragma unroll
    for (int k = 0; k < SREG; k++) p[k] = 0.f;
#pragma unroll
    for (int c = 0; c < 8; c++) {
      H8 wh_c;
      wh_c.v = *(const h8*)(W16 + 8192 + e * 64 + c * 8);
#pragma unroll
      for (int k = 0; k < SREG; k++) {
        int s = srow + 8 * k;
        if (s < S) {
          H8 fc;
          fc.v = *(const h8*)(fb + s * FFN_ + c * 8);
#pragma unroll
          for (int j = 0; j < 4; j++) p[k] = fdot2(fc.h[j], wh_c.h[j], p[k]);
        }
      }
    }
#pragma unroll
    for (int k = 0; k < SREG; k++) {
      int s = srow + 8 * k;
      if (s < S) {
        float a = p[k];
        float ss = red32(a * a);
        xr[seq][k] += a * rsqrtf(ss * (1.0f / E_) + 1e-6f) * nw3;
        Xb[s * 32 + e] = xr[seq][k];
      }
    }
  }
}

// ================= TEMPORAL: round-6 structure (1 seq/block) =================
// LDS (halves): [h S*32 | q->v S*32 | k S*32] = 24576 B -> 6 blocks/CU;
// grid 1072 = 4.19/CU -> single round.
__global__ __launch_bounds__(256, 6) void attn_temporal_kernel(
    float* __restrict__ X, const _Float16* __restrict__ W16,
    const float* __restrict__ norm4, const float* __restrict__ qkn) {
  constexpr int S = T_;
  constexpr int SREG = S / 8;
  __shared__ __align__(16) _Float16 smem[S * 96];
  _Float16* hbuf = smem;            // h -> o -> h2
  _Float16* qh = smem + S * 32;     // q -> v
  _Float16* kh = smem + S * 64;     // k
  _Float16* ffnb = qh;              // ffn overlay

  const int tid = threadIdx.x;
  const int e = tid & 31;
  const int srow = tid >> 5;

  const int b = blockIdx.x / SLOTS_;
  const int slot = blockIdx.x % SLOTS_;
  const int base = (b * T_ * SLOTS_ + slot) * E_;
  const int stride = SLOTS_ * E_;

  const float nw0 = norm4[e], nw1 = norm4[E_ + e], nw2 = norm4[2 * E_ + e],
              nw3 = norm4[3 * E_ + e];

  // ---- phase 1 ----
  float xr[SREG];
#pragma unroll
  for (int k = 0; k < SREG; k++) {
    int s = srow + 8 * k;
    xr[k] = X[base + s * stride + e];
    float ss = red32(xr[k] * xr[k]);
    hbuf[s * 32 + e] = (_Float16)(xr[k] * rsqrtf(ss * (1.0f / E_) + 1e-6f) * nw0);
  }
  __syncthreads();

  const int hd = e & 7;
  const float theta = exp2f(-(float)(hd & 3) * 3.3219280948873623f);

  // ---- phase 2a: q ----
  {
    const float qw = qkn[hd];
    const float qscale = 0.35355339059327373f * 1.4426950408889634f;
    H8 wq[4];
    {
      const h8* wqp = (const h8*)(W16 + e * 32);
#pragma unroll
      for (int j = 0; j < 4; j++) wq[j].v = wqp[j];
    }
    for (int idx = tid; idx < S * E_; idx += 256) {
      int s = idx >> 5;
      const H8* hrow = (const H8*)(hbuf + s * 32);
      float aq = 0.f;
#pragma unroll
      for (int c = 0; c < 4; c++) {
        H8 hc = hrow[c];
#pragma unroll
        for (int j = 0; j < 4; j++) aq = fdot2(hc.h[j], wq[c].h[j], aq);
      }
      float qss = red8(aq * aq);
      float qv = aq * rsqrtf(qss * (1.0f / HD_) + 1e-6f) * qw;
      float ang = (float)s * theta;
      float c, sn;
      __sincosf(ang, &sn, &c);
      float qp2 = __shfl_xor(qv, 4);
      qv = (hd < 4) ? (qv * c - qp2 * sn) : (qv * c + qp2 * sn);
      qh[s * 32 + e] = (_Float16)(qv * qscale);
    }
  }

  // ---- phase 2b: k ----
  {
    const float kw = qkn[8 + hd];
    H8 wk[4];
    {
      const h8* wkp = (const h8*)(W16 + 1024 + e * 32);
#pragma unroll
      for (int j = 0; j < 4; j++) wk[j].v = wkp[j];
    }
    for (int idx = tid; idx < S * E_; idx += 256) {
      int s = idx >> 5;
      const H8* hrow = (const H8*)(hbuf + s * 32);
      float ak = 0.f;
#pragma unroll
      for (int c = 0; c < 4; c++) {
        H8 hc = hrow[c];
#pragma unroll
        for (int j = 0; j < 4; j++) ak = fdot2(hc.h[j], wk[c].h[j], ak);
      }
      float kss = red8(ak * ak);
      float kv = ak * rsqrtf(kss * (1.0f / HD_) + 1e-6f) * kw;
      float ang = (float)s * theta;
      float c, sn;
      __sincosf(ang, &sn, &c);
      float kp2 = __shfl_xor(kv, 4);
      kv = (hd < 4) ? (kv * c - kp2 * sn) : (kv * c + kp2 * sn);
      kh[s * 32 + e] = (_Float16)kv;
    }
  }
  __syncthreads();

  // ---- phase 3a: stash q rows in regs ----
  const int qi = tid >> 1;
  const int hp = tid & 1;
  H8 qa, qb;
  {
    const _Float16* qp = qh + qi * 32 + hp * 16;
    qa.v = *(const h8*)qp;
    qb.v = *(const h8*)(qp + 8);
  }
  __syncthreads();

  // ---- phase 3b: v = h @ Wv -> qh ----
  {
    H8 wv[4];
    {
      const h8* wvp = (const h8*)(W16 + 2048 + e * 32);
#pragma unroll
      for (int j = 0; j < 4; j++) wv[j].v = wvp[j];
    }
    for (int idx = tid; idx < S * E_; idx += 256) {
      int s = idx >> 5;
      const H8* hrow = (const H8*)(hbuf + s * 32);
      float av = 0.f;
#pragma unroll
      for (int c = 0; c < 4; c++) {
        H8 hc = hrow[c];
#pragma unroll
        for (int j = 0; j < 4; j++) av = fdot2(hc.h[j], wv[c].h[j], av);
      }
      qh[s * 32 + e] = (_Float16)av;
    }
  }
  __syncthreads();

  // ---- phase 3c: attention ----
  {
    float l0 = 0.f, l1 = 0.f;
    h2 acc[8] = {};
    const _Float16* kp = kh + hp * 16;
    const _Float16* vp = qh + hp * 16;
#pragma unroll 4
    for (int k = 0; k < S; k++) {
      H8 ka, kb, va, vb;
      ka.v = *(const h8*)kp;
      kb.v = *(const h8*)(kp + 8);
      va.v = *(const h8*)vp;
      vb.v = *(const h8*)(vp + 8);
      kp += 32; vp += 32;
      float s0 = fdot2(qa.h[0], ka.h[0], fdot2(qa.h[1], ka.h[1],
                 fdot2(qa.h[2], ka.h[2], fdot2(qa.h[3], ka.h[3], 0.f))));
      float s1 = fdot2(qb.h[0], kb.h[0], fdot2(qb.h[1], kb.h[1],
                 fdot2(qb.h[2], kb.h[2], fdot2(qb.h[3], kb.h[3], 0.f))));
      float e0 = __builtin_amdgcn_exp2f(s0);
      float e1 = __builtin_amdgcn_exp2f(s1);
      l0 += e0; l1 += e1;
      h2 p0 = pkrtz(e0, e0);
      h2 p1 = pkrtz(e1, e1);
      acc[0] += p0 * va.h[0]; acc[1] += p0 * va.h[1];
      acc[2] += p0 * va.h[2]; acc[3] += p0 * va.h[3];
      acc[4] += p1 * vb.h[0]; acc[5] += p1 * vb.h[1];
      acc[6] += p1 * vb.h[2]; acc[7] += p1 * vb.h[3];
    }
    float iv0 = 1.0f / l0, iv1 = 1.0f / l1;
    h2 il0 = pkrtz(iv0, iv0), il1 = pkrtz(iv1, iv1);
    H8 o0, o1;
#pragma unroll
    for (int j = 0; j < 4; j++) {
      o0.h[j] = acc[j] * il0;
      o1.h[j] = acc[4 + j] * il1;
    }
    _Float16* op = hbuf + qi * 32 + hp * 16;
    *(h8*)op = o0.v;
    *(h8*)(op + 8) = o1.v;
  }
  __syncthreads();

  // ---- phase 4 ----
  {
    float p[SREG];
#pragma unroll
    for (int k = 0; k < SREG; k++) p[k] = 0.f;
#pragma unroll
    for (int c = 0; c < 4; c++) {
      H8 wo_c;
      wo_c.v = *(const h8*)(W16 + 3072 + e * 32 + c * 8);
#pragma unroll
      for (int k = 0; k < SREG; k++) {
        int s = srow + 8 * k;
        H8 oc;
        oc.v = *(const h8*)(hbuf + s * 32 + c * 8);
#pragma unroll
        for (int j = 0; j < 4; j++) p[k] = fdot2(oc.h[j], wo_c.h[j], p[k]);
      }
    }
#pragma unroll
    for (int k = 0; k < SREG; k++) {
      int s = srow + 8 * k;
      float a = p[k];
      float ss = red32(a * a);
      xr[k] += a * rsqrtf(ss * (1.0f / E_) + 1e-6f) * nw1;
      float hx = xr[k];
      float s2s = red32(hx * hx);
      hbuf[s * 32 + e] = (_Float16)(hx * rsqrtf(s2s * (1.0f / E_) + 1e-6f) * nw2);
    }
  }
  __syncthreads();

  // ---- phase 5a ----
  {
    const int f = tid & 63;
    H8 wg[4];
    {
      const h8* a8 = (const h8*)(W16 + 4096 + f * 32);
#pragma unroll
      for (int j = 0; j < 4; j++) wg[j].v = a8[j];
    }
    for (int idx = tid; idx < S * FFN_; idx += 256) {
      int s = idx >> 6;
      const H8* hrow = (const H8*)(hbuf + s * 32);
      float gq = 0.f;
#pragma unroll
      for (int c = 0; c < 4; c++) {
        H8 hc = hrow[c];
#pragma unroll
        for (int j = 0; j < 4; j++) gq = fdot2(hc.h[j], wg[c].h[j], gq);
      }
      float sg = gq / (1.0f + __expf(-gq));
      ffnb[s * FFN_ + f] = (_Float16)sg;
    }
  }

  // ---- phase 5b ----
  {
    const int f = tid & 63;
    H8 wl[4];
    {
      const h8* b8 = (const h8*)(W16 + 6144 + f * 32);
#pragma unroll
      for (int j = 0; j < 4; j++) wl[j].v = b8[j];
    }
    for (int idx = tid; idx < S * FFN_; idx += 256) {
      int s = idx >> 6;
      const H8* hrow = (const H8*)(hbuf + s * 32);
      float vv = 0.f;
#pragma unroll
      for (int c = 0; c < 4; c++) {
        H8 hc = hrow[c];
#pragma unroll
        for (int j = 0; j < 4; j++) vv = fdot2(hc.h[j], wl[c].h[j], vv);
      }
      float sg = (float)ffnb[s * FFN_ + f];
      ffnb[s * FFN_ + f] = (_Float16)(sg * vv);
    }
  }
  __syncthreads();

  // ---- phase 6 ----
  {
    float p[SREG];
#pragma unroll
    for (int k = 0; k < SREG; k++) p[k] = 0.f;
#pragma unroll
    for (int c = 0; c < 8; c++) {
      H8 wh_c;
      wh_c.v = *(const h8*)(W16 + 8192 + e * 64 + c * 8);
#pragma unroll
      for (int k = 0; k < SREG; k++) {
        int s = srow + 8 * k;
        H8 fc;
        fc.v = *(const h8*)(ffnb + s * FFN_ + c * 8);
#pragma unroll
        for (int j = 0; j < 4; j++) p[k] = fdot2(fc.h[j], wh_c.h[j], p[k]);
      }
    }
#pragma unroll
    for (int k = 0; k < SREG; k++) {
      int s = srow + 8 * k;
      float a = p[k];
      float ss = red32(a * a);
      xr[k] += a * rsqrtf(ss * (1.0f / E_) + 1e-6f) * nw3;
      X[base + s * stride + e] = xr[k];
    }
  }
}

// ---------------- final norm + output extraction ----------------
__global__ __launch_bounds__(256) void final_kernel(const float* __restrict__ X,
                                                    const float* __restrict__ fnw,
                                                    float* __restrict__ out) {
  int tok = blockIdx.x * 8 + (threadIdx.x >> 5);
  int e = threadIdx.x & 31;
  if (tok >= B_ * 3) return;
  int b = tok / 3, j = tok % 3;
  const float* xp = X + ((size_t)(b * T_ + (T_ - 1)) * SLOTS_ + OBS_ + j) * E_;
  float v = xp[e];
  float ss = red32(v * v);
  out[j * (B_ * E_) + b * E_ + e] = v * rsqrtf(ss * (1.0f / E_) + 1e-6f) * fnw[e];
}

extern "C" void kernel_launch(void* const* d_in, const int* in_sizes, int n_in,
                              void* d_out, int out_size, void* d_ws, size_t ws_size,
                              hipStream_t stream) {
  (void)in_sizes; (void)n_in; (void)out_size; (void)ws_size;
  const float* obs          = (const float*)d_in[0];
  const float* W_val        = (const float*)d_in[1];
  const float* b_val        = (const float*)d_in[2];
  const float* input_norm_w = (const float*)d_in[3];
  const float* dim_embed    = (const float*)d_in[4];
  const float* cls_tokens   = (const float*)d_in[5];
  const float* final_norm_w = (const float*)d_in[6];
  const float* s_n4   = (const float*)d_in[14];
  const float* s_qkn  = (const float*)d_in[15];
  const float* t_n4   = (const float*)d_in[23];
  const float* t_qkn  = (const float*)d_in[24];

  float* X = (float*)d_ws;  // B*T*SLOTS*E floats = 17.56 MB
  _Float16* W16 = (_Float16*)((char*)d_ws + X_BYTES);  // 5*10240 halves
  float* out = (float*)d_out;

  WPtrs wp;
  wp.sWq   = (const float*)d_in[7];
  wp.sWk   = (const float*)d_in[8];
  wp.sWv   = (const float*)d_in[9];
  wp.sWo   = (const float*)d_in[10];
  wp.sWg   = (const float*)d_in[11];
  wp.sWvl  = (const float*)d_in[12];
  wp.sWout = (const float*)d_in[13];
  wp.tWq   = (const float*)d_in[16];
  wp.tWk   = (const float*)d_in[17];
  wp.tWv   = (const float*)d_in[18];
  wp.tWo   = (const float*)d_in[19];
  wp.tWg   = (const float*)d_in[20];
  wp.tWvl  = (const float*)d_in[21];
  wp.tWout = (const float*)d_in[22];
  cvt_weights_kernel<<<100, 256, 0, stream>>>(wp, W16);

  const int total_tokens = B_ * T_ * SLOTS_;
  embed_kernel<<<(total_tokens + 7) / 8, 256, 0, stream>>>(
      obs, W_val, b_val, input_norm_w, dim_embed, cls_tokens, X);

  const int N4 = 4 * E_;   // 128
  const int QN = 2 * HD_;  // 16

#define SPATIAL(i)                                                     \
  attn_spatial_kernel<<<B_ * T_ / 2, 256, 0, stream>>>(                \
      X, W16 + (i)*WBLK, s_n4 + (i)*N4, s_qkn + (i)*QN)
#define TEMPORAL(i)                                                    \
  attn_temporal_kernel<<<B_ * SLOTS_, 256, 0, stream>>>(               \
      X, W16 + (3 + (i)) * WBLK, t_n4 + (i)*N4, t_qkn + (i)*QN)

  SPATIAL(0);
  TEMPORAL(0);
  SPATIAL(1);
  TEMPORAL(1);
  SPATIAL(2);

#undef SPATIAL
#undef TEMPORAL

  final_kernel<<<6, 256, 0, stream>>>(X, final_norm_w, out);
}

// Round 9
// 424.301 us; speedup vs baseline: 2.7720x; 1.3587x over previous
//
#include <hip/hip_runtime.h>

#define B_ 16
#define T_ 128
#define OBS_ 64
#define SLOTS_ 67
#define E_ 32
#define H_ 4
#define HD_ 8
#define FFN_ 64

typedef _Float16 h2 __attribute__((ext_vector_type(2)));
typedef _Float16 h8 __attribute__((ext_vector_type(8)));
typedef __fp16 mh8 __attribute__((ext_vector_type(8)));
typedef float fx4 __attribute__((ext_vector_type(4)));
union H8 { h8 v; h2 h[4]; };

// fp16 weight block layout (halves): Wq 0 | Wk 1024 | Wv 2048 | Wo 3072 |
// Wg 4096 | Wvl 6144 | Wout 8192  (10240 halves per transformer block)
#define WBLK 10240
#define X_BYTES (B_ * T_ * SLOTS_ * E_ * 4)  // 17,563,648

__device__ __forceinline__ float red32(float v) {
  v += __shfl_xor(v, 16); v += __shfl_xor(v, 8); v += __shfl_xor(v, 4);
  v += __shfl_xor(v, 2);  v += __shfl_xor(v, 1);
  return v;
}
__device__ __forceinline__ float red8(float v) {
  v += __shfl_xor(v, 4); v += __shfl_xor(v, 2); v += __shfl_xor(v, 1);
  return v;
}
__device__ __forceinline__ float fdot2(h2 a, h2 b, float c) {
  return __builtin_amdgcn_fdot2(a, b, c, false);
}
__device__ __forceinline__ h2 pkrtz(float x, float y) {
  return __builtin_bit_cast(h2, __builtin_amdgcn_cvt_pkrtz(x, y));
}
__device__ __forceinline__ fx4 mfma16(h8 a, h8 b, fx4 c) {
  return __builtin_amdgcn_mfma_f32_16x16x32_f16(
      __builtin_bit_cast(mh8, a), __builtin_bit_cast(mh8, b), c, 0, 0, 0);
}

// ---------------- weight pre-conversion to fp16 ----------------
struct WPtrs {
  const float *sWq, *sWk, *sWv, *sWo, *sWg, *sWvl, *sWout;
  const float *tWq, *tWk, *tWv, *tWo, *tWg, *tWvl, *tWout;
};

__global__ __launch_bounds__(256) void cvt_weights_kernel(WPtrs p, _Float16* dst) {
  int i = blockIdx.x * 256 + threadIdx.x;  // pair index
  const int total_pairs = 5 * WBLK / 2;    // 25600
  if (i >= total_pairs) return;
  int blk = i / (WBLK / 2);
  int f = (i % (WBLK / 2)) * 2;
  bool sp = blk < 3;
  int bi = sp ? blk : blk - 3;
  const float* src;
  int o;
  if (f < 1024)      { src = (sp ? p.sWq : p.tWq) + bi * 1024;  o = f; }
  else if (f < 2048) { src = (sp ? p.sWk : p.tWk) + bi * 1024;  o = f - 1024; }
  else if (f < 3072) { src = (sp ? p.sWv : p.tWv) + bi * 1024;  o = f - 2048; }
  else if (f < 4096) { src = (sp ? p.sWo : p.tWo) + bi * 1024;  o = f - 3072; }
  else if (f < 6144) { src = (sp ? p.sWg : p.tWg) + bi * 2048;  o = f - 4096; }
  else if (f < 8192) { src = (sp ? p.sWvl : p.tWvl) + bi * 2048; o = f - 6144; }
  else               { src = (sp ? p.sWout : p.tWout) + bi * 2048; o = f - 8192; }
  ((h2*)dst)[i] = pkrtz(src[o], src[o + 1]);
}

// ---------------- embed + input rmsnorm ----------------
__global__ __launch_bounds__(256) void embed_kernel(
    const float* __restrict__ obs, const float* __restrict__ Wval,
    const float* __restrict__ bval, const float* __restrict__ innw,
    const float* __restrict__ dimemb, const float* __restrict__ cls,
    float* __restrict__ X) {
  int tok = blockIdx.x * 8 + (threadIdx.x >> 5);
  int e = threadIdx.x & 31;
  const int total = B_ * T_ * SLOTS_;
  if (tok >= total) return;
  int slot = tok % SLOTS_;
  int bt = tok / SLOTS_;
  float v;
  if (slot < OBS_) {
    float o = obs[bt * OBS_ + slot];
    v = o * Wval[e] + bval[e] + dimemb[slot * E_ + e];
  } else {
    v = cls[(slot - OBS_) * E_ + e];
  }
  float ss = red32(v * v);
  X[tok * E_ + e] = v * rsqrtf(ss * (1.0f / E_) + 1e-6f) * innw[e];
}

// ================= full attention block, MFMA GEMM phases =================
// SV = valid rows, SP = padded rows (multiple of 16).
// LDS (halves): [hb SP*32 | qb SP*32 | kb SP*32 | vb SP*32].
//   hb: h -> o -> h2 ; ffnb (SV*64) overlays qb+kb ; ao scratch = qb ;
//   out scratch = vb.  Temporal 32 KB -> 5 blk/CU; spatial 36.9 KB -> 4 blk/CU.
// Spatial handles 2 sequences as one contiguous 134-row slab (GEMMs are
// row-independent; only attention separates the sequences).
template <int SV, int SP, bool TEMPORAL>
__device__ __forceinline__ void block_body(
    float* __restrict__ X, const _Float16* __restrict__ W16,
    const float* __restrict__ norm4, const float* __restrict__ qkn, int bid) {
  constexpr int SREG = (SV + 7) / 8;
  constexpr int MT = SP / 16;
  __shared__ __align__(16) _Float16 smem[SP * 128];
  _Float16* hb = smem;
  _Float16* qb = smem + SP * 32;
  _Float16* kb = smem + SP * 64;
  _Float16* vb = smem + SP * 96;
  _Float16* ffnb = qb;  // SV*64 <= SP*64 halves over qb+kb
  _Float16* aob = qb;   // ao scratch (q dead after attention)
  _Float16* outb = vb;  // out scratch (v dead after attention)

  const int tid = threadIdx.x;
  const int e = tid & 31, srow = tid >> 5;
  const int l = tid & 63, wv = tid >> 6;
  const int lm = l & 15, lq = l >> 4, hd = l & 7;

  int base, stride;
  if (TEMPORAL) {
    int b = bid / SLOTS_;
    int slot = bid % SLOTS_;
    base = (b * T_ * SLOTS_ + slot) * E_;
    stride = SLOTS_ * E_;
  } else {
    base = bid * 2 * SLOTS_ * E_;  // contiguous 134-row slab
    stride = E_;
  }

  const float nw0 = norm4[e], nw1 = norm4[E_ + e], nw2 = norm4[2 * E_ + e],
              nw3 = norm4[3 * E_ + e];
  const fx4 fz = {0.f, 0.f, 0.f, 0.f};
  const float qw = qkn[hd], kw = qkn[8 + hd];
  const float qscale = 0.35355339059327373f * 1.4426950408889634f;  // 1/sqrt(8)*log2e
  float theta = 0.f;
  if (TEMPORAL) theta = exp2f(-(float)(hd & 3) * 3.3219280948873623f);

  // ---- phase 1: x -> regs; h = rmsnorm(x) -> hb (fp16) ----
  float xr[SREG];
#pragma unroll
  for (int k = 0; k < SREG; k++) {
    int r = srow + 8 * k;
    if (SV % 8 == 0 || r < SV) {
      xr[k] = X[base + r * stride + e];
      float ss = red32(xr[k] * xr[k]);
      hb[r * 32 + e] = (_Float16)(xr[k] * rsqrtf(ss * (1.0f / E_) + 1e-6f) * nw0);
    }
  }
  __syncthreads();

  // ---- phase 2: q/k/v = MFMA(h, W) + head rmsnorm + RoPE ----
  for (int mt = wv; mt < MT; mt += 4) {
    h8 aH = *(const h8*)(hb + (mt * 16 + lm) * 32 + lq * 8);
    float rc[4], rs[4];
    if (TEMPORAL) {
#pragma unroll
      for (int r = 0; r < 4; r++) {
        float ang = (float)(mt * 16 + lq * 4 + r) * theta;
        __sincosf(ang, &rs[r], &rc[r]);
      }
    }
#pragma unroll
    for (int nt = 0; nt < 2; nt++) {
      const int d = nt * 16 + lm;
      h8 bq = *(const h8*)(W16 + (nt * 16 + lm) * 32 + lq * 8);
      h8 bk = *(const h8*)(W16 + 1024 + (nt * 16 + lm) * 32 + lq * 8);
      h8 bv = *(const h8*)(W16 + 2048 + (nt * 16 + lm) * 32 + lq * 8);
      fx4 aq = mfma16(aH, bq, fz);
      fx4 ak = mfma16(aH, bk, fz);
      fx4 av = mfma16(aH, bv, fz);
#pragma unroll
      for (int r = 0; r < 4; r++) {
        int s = mt * 16 + lq * 4 + r;
        float q1 = aq[r], k1 = ak[r];
        float qv = q1 * rsqrtf(red8(q1 * q1) * 0.125f + 1e-6f) * qw;
        float kv = k1 * rsqrtf(red8(k1 * k1) * 0.125f + 1e-6f) * kw;
        if (TEMPORAL) {
          float qp = __shfl_xor(qv, 4);
          float kp = __shfl_xor(kv, 4);
          qv = (hd < 4) ? (qv * rc[r] - qp * rs[r]) : (qv * rc[r] + qp * rs[r]);
          kv = (hd < 4) ? (kv * rc[r] - kp * rs[r]) : (kv * rc[r] + kp * rs[r]);
        }
        if (SV == SP || s < SV) {
          qb[s * 32 + d] = (_Float16)(qv * qscale);  // exp2-ready
          kb[s * 32 + d] = (_Float16)kv;
          vb[s * 32 + d] = (_Float16)av[r];
        }
      }
    }
  }
  __syncthreads();

  // ---- phase 3: attention (scalar, single-pass softmax; scores bounded) ----
  {
    constexpr int NITEM = 2 * SV;
    constexpr int NPASS = (NITEM + 255) / 256;
    constexpr int KLEN = TEMPORAL ? SV : SLOTS_;
#pragma unroll
    for (int pass = 0; pass < NPASS; pass++) {
      int I = tid + pass * 256;
      if (I < NITEM) {
        int r = I >> 1, hp = I & 1;
        int kb0 = TEMPORAL ? 0 : (r >= SLOTS_ ? SLOTS_ : 0);
        const _Float16* qp_ = qb + r * 32 + hp * 16;
        H8 qfa, qfb;
        qfa.v = *(const h8*)qp_;
        qfb.v = *(const h8*)(qp_ + 8);
        float l0 = 0.f, l1 = 0.f;
        h2 acc[8] = {};
        const _Float16* kp_ = kb + kb0 * 32 + hp * 16;
        const _Float16* vp_ = vb + kb0 * 32 + hp * 16;
#pragma unroll 4
        for (int k = 0; k < KLEN; k++) {
          H8 kfa, kfb, vfa, vfb;
          kfa.v = *(const h8*)kp_;
          kfb.v = *(const h8*)(kp_ + 8);
          vfa.v = *(const h8*)vp_;
          vfb.v = *(const h8*)(vp_ + 8);
          kp_ += 32; vp_ += 32;
          float s0 = fdot2(qfa.h[0], kfa.h[0], fdot2(qfa.h[1], kfa.h[1],
                     fdot2(qfa.h[2], kfa.h[2], fdot2(qfa.h[3], kfa.h[3], 0.f))));
          float s1 = fdot2(qfb.h[0], kfb.h[0], fdot2(qfb.h[1], kfb.h[1],
                     fdot2(qfb.h[2], kfb.h[2], fdot2(qfb.h[3], kfb.h[3], 0.f))));
          float e0 = __builtin_amdgcn_exp2f(s0);
          float e1 = __builtin_amdgcn_exp2f(s1);
          l0 += e0; l1 += e1;
          h2 p0 = pkrtz(e0, e0);
          h2 p1 = pkrtz(e1, e1);
          acc[0] += p0 * vfa.h[0]; acc[1] += p0 * vfa.h[1];
          acc[2] += p0 * vfa.h[2]; acc[3] += p0 * vfa.h[3];
          acc[4] += p1 * vfb.h[0]; acc[5] += p1 * vfb.h[1];
          acc[6] += p1 * vfb.h[2]; acc[7] += p1 * vfb.h[3];
        }
        float iv0 = 1.0f / l0, iv1 = 1.0f / l1;
        h2 il0 = pkrtz(iv0, iv0), il1 = pkrtz(iv1, iv1);
        H8 o0, o1;
#pragma unroll
        for (int j = 0; j < 4; j++) {
          o0.h[j] = acc[j] * il0;
          o1.h[j] = acc[4 + j] * il1;
        }
        _Float16* op = hb + r * 32 + hp * 16;  // h dead -> o
        *(h8*)op = o0.v;
        *(h8*)(op + 8) = o1.v;
      }
    }
  }
  __syncthreads();

  // ---- phase 4: ao = MFMA(o, Wo) -> aob (fp16) ----
  for (int mt = wv; mt < MT; mt += 4) {
    h8 aO = *(const h8*)(hb + (mt * 16 + lm) * 32 + lq * 8);
#pragma unroll
    for (int nt = 0; nt < 2; nt++) {
      h8 bo = *(const h8*)(W16 + 3072 + (nt * 16 + lm) * 32 + lq * 8);
      fx4 acc = mfma16(aO, bo, fz);
#pragma unroll
      for (int r = 0; r < 4; r++) {
        int s = mt * 16 + lq * 4 + r;
        if (SV == SP || s < SV) aob[s * 32 + nt * 16 + lm] = (_Float16)acc[r];
      }
    }
  }
  __syncthreads();
  // ---- phase 4 epilogue: x += rms(ao); h2 = rms(x) -> hb ----
#pragma unroll
  for (int k = 0; k < SREG; k++) {
    int r = srow + 8 * k;
    if (SV % 8 == 0 || r < SV) {
      float a = (float)aob[r * 32 + e];
      float ss = red32(a * a);
      xr[k] += a * rsqrtf(ss * (1.0f / E_) + 1e-6f) * nw1;
      float hx = xr[k];
      float s2 = red32(hx * hx);
      hb[r * 32 + e] = (_Float16)(hx * rsqrtf(s2 * (1.0f / E_) + 1e-6f) * nw2);
    }
  }
  __syncthreads();

  // ---- phase 5: ffn = silu(MFMA(h2,Wg)) * MFMA(h2,Wvl) -> ffnb ----
  for (int mt = wv; mt < MT; mt += 4) {
    h8 aH2 = *(const h8*)(hb + (mt * 16 + lm) * 32 + lq * 8);
#pragma unroll
    for (int nt = 0; nt < 4; nt++) {
      h8 bg = *(const h8*)(W16 + 4096 + (nt * 16 + lm) * 32 + lq * 8);
      h8 bl = *(const h8*)(W16 + 6144 + (nt * 16 + lm) * 32 + lq * 8);
      fx4 g = mfma16(aH2, bg, fz);
      fx4 vvv = mfma16(aH2, bl, fz);
#pragma unroll
      for (int r = 0; r < 4; r++) {
        int s = mt * 16 + lq * 4 + r;
        if (SV == SP || s < SV) {
          float gg = g[r];
          float sg = gg / (1.0f + __expf(-gg));
          ffnb[s * 64 + nt * 16 + lm] = (_Float16)(sg * vvv[r]);
        }
      }
    }
  }
  __syncthreads();

  // ---- phase 6: out = MFMA(ffn, Wout^T) [K=64 via 2 chained] -> outb ----
  for (int mt = wv; mt < MT; mt += 4) {
    h8 a0 = *(const h8*)(ffnb + (mt * 16 + lm) * 64 + lq * 8);
    h8 a1 = *(const h8*)(ffnb + (mt * 16 + lm) * 64 + 32 + lq * 8);
#pragma unroll
    for (int nt = 0; nt < 2; nt++) {
      h8 b0 = *(const h8*)(W16 + 8192 + (nt * 16 + lm) * 64 + lq * 8);
      h8 b1 = *(const h8*)(W16 + 8192 + (nt * 16 + lm) * 64 + 32 + lq * 8);
      fx4 acc = mfma16(a1, b1, mfma16(a0, b0, fz));
#pragma unroll
      for (int r = 0; r < 4; r++) {
        int s = mt * 16 + lq * 4 + r;
        if (SV == SP || s < SV) outb[s * 32 + nt * 16 + lm] = (_Float16)acc[r];
      }
    }
  }
  __syncthreads();
  // ---- phase 6 epilogue: x += rms(out), store ----
#pragma unroll
  for (int k = 0; k < SREG; k++) {
    int r = srow + 8 * k;
    if (SV % 8 == 0 || r < SV) {
      float a = (float)outb[r * 32 + e];
      float ss = red32(a * a);
      xr[k] += a * rsqrtf(ss * (1.0f / E_) + 1e-6f) * nw3;
      X[base + r * stride + e] = xr[k];
    }
  }
}

__global__ __launch_bounds__(256, 4) void attn_spatial_kernel(
    float* __restrict__ X, const _Float16* __restrict__ W16,
    const float* __restrict__ norm4, const float* __restrict__ qkn) {
  block_body<2 * SLOTS_, 144, false>(X, W16, norm4, qkn, blockIdx.x);
}

__global__ __launch_bounds__(256, 4) void attn_temporal_kernel(
    float* __restrict__ X, const _Float16* __restrict__ W16,
    const float* __restrict__ norm4, const float* __restrict__ qkn) {
  block_body<T_, 128, true>(X, W16, norm4, qkn, blockIdx.x);
}

// ---------------- final norm + output extraction ----------------
__global__ __launch_bounds__(256) void final_kernel(const float* __restrict__ X,
                                                    const float* __restrict__ fnw,
                                                    float* __restrict__ out) {
  int tok = blockIdx.x * 8 + (threadIdx.x >> 5);
  int e = threadIdx.x & 31;
  if (tok >= B_ * 3) return;
  int b = tok / 3, j = tok % 3;
  const float* xp = X + ((size_t)(b * T_ + (T_ - 1)) * SLOTS_ + OBS_ + j) * E_;
  float v = xp[e];
  float ss = red32(v * v);
  out[j * (B_ * E_) + b * E_ + e] = v * rsqrtf(ss * (1.0f / E_) + 1e-6f) * fnw[e];
}

extern "C" void kernel_launch(void* const* d_in, const int* in_sizes, int n_in,
                              void* d_out, int out_size, void* d_ws, size_t ws_size,
                              hipStream_t stream) {
  (void)in_sizes; (void)n_in; (void)out_size; (void)ws_size;
  const float* obs          = (const float*)d_in[0];
  const float* W_val        = (const float*)d_in[1];
  const float* b_val        = (const float*)d_in[2];
  const float* input_norm_w = (const float*)d_in[3];
  const float* dim_embed    = (const float*)d_in[4];
  const float* cls_tokens   = (const float*)d_in[5];
  const float* final_norm_w = (const float*)d_in[6];
  const float* s_n4   = (const float*)d_in[14];
  const float* s_qkn  = (const float*)d_in[15];
  const float* t_n4   = (const float*)d_in[23];
  const float* t_qkn  = (const float*)d_in[24];

  float* X = (float*)d_ws;  // B*T*SLOTS*E floats = 17.56 MB
  _Float16* W16 = (_Float16*)((char*)d_ws + X_BYTES);  // 5*10240 halves
  float* out = (float*)d_out;

  WPtrs wp;
  wp.sWq   = (const float*)d_in[7];
  wp.sWk   = (const float*)d_in[8];
  wp.sWv   = (const float*)d_in[9];
  wp.sWo   = (const float*)d_in[10];
  wp.sWg   = (const float*)d_in[11];
  wp.sWvl  = (const float*)d_in[12];
  wp.sWout = (const float*)d_in[13];
  wp.tWq   = (const float*)d_in[16];
  wp.tWk   = (const float*)d_in[17];
  wp.tWv   = (const float*)d_in[18];
  wp.tWo   = (const float*)d_in[19];
  wp.tWg   = (const float*)d_in[20];
  wp.tWvl  = (const float*)d_in[21];
  wp.tWout = (const float*)d_in[22];
  cvt_weights_kernel<<<100, 256, 0, stream>>>(wp, W16);

  const int total_tokens = B_ * T_ * SLOTS_;
  embed_kernel<<<(total_tokens + 7) / 8, 256, 0, stream>>>(
      obs, W_val, b_val, input_norm_w, dim_embed, cls_tokens, X);

  const int N4 = 4 * E_;   // 128
  const int QN = 2 * HD_;  // 16

#define SPATIAL(i)                                                     \
  attn_spatial_kernel<<<B_ * T_ / 2, 256, 0, stream>>>(                \
      X, W16 + (i)*WBLK, s_n4 + (i)*N4, s_qkn + (i)*QN)
#define TEMPORAL(i)                                                    \
  attn_temporal_kernel<<<B_ * SLOTS_, 256, 0, stream>>>(               \
      X, W16 + (3 + (i)) * WBLK, t_n4 + (i)*N4, t_qkn + (i)*QN)

  SPATIAL(0);
  TEMPORAL(0);
  SPATIAL(1);
  TEMPORAL(1);
  SPATIAL(2);

#undef SPATIAL
#undef TEMPORAL

  final_kernel<<<6, 256, 0, stream>>>(X, final_norm_w, out);
}